// Round 1
// baseline (2285.478 us; speedup 1.0000x reference)
//
#include <hip/hip_runtime.h>
#include <math.h>

// Shapes (fixed for this problem)
#define NT 1024      // tokens
#define CA 768       // c_a
#define CS 384       // c_s
#define CZ 128       // c_z
#define NH 16        // heads
#define HD 48        // head dim

__device__ __forceinline__ float sigmoidf_(float x) { return 1.0f / (1.0f + expf(-x)); }

// ---------------------------------------------------------------------------
// Generic row LayerNorm: out = (x-mean)*rsqrt(var+eps) [*g + b]
// one block (256 thr) per row
// ---------------------------------------------------------------------------
__global__ __launch_bounds__(256) void ln_kernel(const float* __restrict__ in,
                                                 float* __restrict__ out,
                                                 const float* __restrict__ g,
                                                 const float* __restrict__ b,
                                                 int C) {
    int row = blockIdx.x;
    const float* x = in + (size_t)row * C;
    float* y = out + (size_t)row * C;
    float sum = 0.f, sq = 0.f;
    for (int c = threadIdx.x; c < C; c += 256) { float v = x[c]; sum += v; sq += v * v; }
#pragma unroll
    for (int off = 32; off > 0; off >>= 1) { sum += __shfl_down(sum, off); sq += __shfl_down(sq, off); }
    __shared__ float s1[4], s2[4], smv[2];
    int wid = threadIdx.x >> 6, lane = threadIdx.x & 63;
    if (lane == 0) { s1[wid] = sum; s2[wid] = sq; }
    __syncthreads();
    if (threadIdx.x == 0) {
        float ts = s1[0] + s1[1] + s1[2] + s1[3];
        float tq = s2[0] + s2[1] + s2[2] + s2[3];
        float m = ts / C;
        float v = tq / C - m * m;
        smv[0] = m; smv[1] = rsqrtf(v + 1e-5f);
    }
    __syncthreads();
    float m = smv[0], r = smv[1];
    if (g) {
        for (int c = threadIdx.x; c < C; c += 256) y[c] = (x[c] - m) * r * g[c] + b[c];
    } else {
        for (int c = threadIdx.x; c < C; c += 256) y[c] = (x[c] - m) * r;
    }
}

// ---------------------------------------------------------------------------
// fp32 GEMM: C[M,N] = A[M,K] @ B[K,N] (+bias[N])
// BM=BN=64, BK=16, 256 threads, 4x4 per thread. M,N,K multiples of 64/64/16.
// ---------------------------------------------------------------------------
__global__ __launch_bounds__(256) void gemm_kernel(const float* __restrict__ A,
                                                   const float* __restrict__ B,
                                                   const float* __restrict__ bias,
                                                   float* __restrict__ C,
                                                   int M, int N, int K) {
    __shared__ float As[16][68];   // [k][m], stride 68 -> float4-aligned, conflict-light
    __shared__ float Bs[16][68];   // [k][n]
    int t = threadIdx.x;
    int n0 = blockIdx.x * 64, m0 = blockIdx.y * 64;
    int ty = t >> 4, tx = t & 15;          // compute mapping: rows ty*4.., cols tx*4..
    int ar = t >> 2, ac4 = (t & 3) * 4;    // A load mapping
    int bkr = t >> 4, bnc = (t & 15) * 4;  // B load mapping
    float acc[4][4] = {};
    for (int k0 = 0; k0 < K; k0 += 16) {
        float4 a4 = *(const float4*)&A[(size_t)(m0 + ar) * K + k0 + ac4];
        float4 b4 = *(const float4*)&B[(size_t)(k0 + bkr) * N + n0 + bnc];
        As[ac4 + 0][ar] = a4.x;
        As[ac4 + 1][ar] = a4.y;
        As[ac4 + 2][ar] = a4.z;
        As[ac4 + 3][ar] = a4.w;
        *(float4*)&Bs[bkr][bnc] = b4;
        __syncthreads();
#pragma unroll
        for (int kk = 0; kk < 16; ++kk) {
            float4 av = *(const float4*)&As[kk][ty * 4];
            float4 bv = *(const float4*)&Bs[kk][tx * 4];
            float am[4] = {av.x, av.y, av.z, av.w};
            float bm[4] = {bv.x, bv.y, bv.z, bv.w};
#pragma unroll
            for (int i = 0; i < 4; ++i)
#pragma unroll
                for (int j = 0; j < 4; ++j) acc[i][j] += am[i] * bm[j];
        }
        __syncthreads();
    }
    float4 bv = {0, 0, 0, 0};
    if (bias) bv = *(const float4*)&bias[n0 + tx * 4];
#pragma unroll
    for (int i = 0; i < 4; ++i) {
        float4 o;
        o.x = acc[i][0] + bv.x; o.y = acc[i][1] + bv.y;
        o.z = acc[i][2] + bv.z; o.w = acc[i][3] + bv.w;
        *(float4*)&C[(size_t)(m0 + ty * 4 + i) * N + n0 + tx * 4] = o;
    }
}

// ---------------------------------------------------------------------------
// z kernel: per (i,j) pair: copy raw z row to out_z; LN(z_row)*zg+zb; dot with
// Wz[128,16] -> S[h, i, j] (pair-bias, pre-transposed to [H,N,N]).
// One wave per pair, 4 pairs per block. Grid = N*N/4.
// ---------------------------------------------------------------------------
__global__ __launch_bounds__(256) void z_bias_copy_kernel(const float* __restrict__ z,
                                                          const float* __restrict__ zg,
                                                          const float* __restrict__ zb,
                                                          const float* __restrict__ Wz,
                                                          float* __restrict__ z_out,
                                                          float* __restrict__ S) {
    __shared__ float sWzT[16][129];  // transposed [h][c], stride 129 breaks conflicts
    __shared__ float sg[128], sb[128];
    __shared__ float ys[4][128];     // normalized row per wave
    int t = threadIdx.x;
    for (int i = t; i < 2048; i += 256) { int c = i >> 4, h = i & 15; sWzT[h][c] = Wz[i]; }
    if (t < 128) { sg[t] = zg[t]; sb[t] = zb[t]; }
    __syncthreads();
    int wid = t >> 6, lane = t & 63;
    int p = blockIdx.x * 4 + wid;  // pair index in [0, NT*NT)
    const float2 v = ((const float2*)(z + (size_t)p * CZ))[lane];
    ((float2*)(z_out + (size_t)p * CZ))[lane] = v;  // passthrough copy
    float sum = v.x + v.y, sq = v.x * v.x + v.y * v.y;
#pragma unroll
    for (int off = 32; off > 0; off >>= 1) { sum += __shfl_down(sum, off); sq += __shfl_down(sq, off); }
    float mean = __shfl(sum, 0) * (1.0f / 128.0f);
    float var = __shfl(sq, 0) * (1.0f / 128.0f) - mean * mean;
    float rstd = rsqrtf(var + 1e-5f);
    int c0 = lane * 2;
    ys[wid][c0]     = (v.x - mean) * rstd * sg[c0] + sb[c0];
    ys[wid][c0 + 1] = (v.y - mean) * rstd * sg[c0 + 1] + sb[c0 + 1];
    __syncthreads();
    // phase 2: lane -> (h = lane>>2, quarter qq = lane&3 covering 32 c's)
    int h = lane >> 2, qq = lane & 3;
    float part = 0.f;
#pragma unroll
    for (int cc = 0; cc < 32; ++cc) {
        int c = qq * 32 + ((cc + qq * 8) & 31);  // rotate start to dodge bank conflicts
        part += ys[wid][c] * sWzT[h][c];
    }
    part += __shfl_down(part, 2);
    part += __shfl_down(part, 1);
    if (qq == 0) {
        int i = p >> 10, j = p & 1023;
        S[((size_t)h << 20) + ((size_t)i << 10) + j] = part;
    }
}

// ---------------------------------------------------------------------------
// scores: S[h,i,j] += (q_i . k_j) * 48^-0.5   (S pre-holds bias)
// grid (NT/32, NT/32, NH), 32x32 tile per block
// ---------------------------------------------------------------------------
__global__ __launch_bounds__(256) void scores_kernel(const float* __restrict__ q,
                                                     const float* __restrict__ k,
                                                     float* __restrict__ S) {
    __shared__ float qs[32][49];
    __shared__ float kst[48][36];  // transposed [d][j]
    int h = blockIdx.z, i0 = blockIdx.y * 32, j0 = blockIdx.x * 32;
    int t = threadIdx.x;
    const float scale = 0.14433756729740643f;  // 48^-0.5
    for (int idx = t; idx < 32 * 48; idx += 256) {
        int r = idx / 48, c = idx % 48;
        qs[r][c] = q[(size_t)(i0 + r) * CA + h * HD + c] * scale;
        kst[c][r] = k[(size_t)(j0 + r) * CA + h * HD + c];
    }
    __syncthreads();
    int r = t >> 3, cg = t & 7;
    float4 acc = {0, 0, 0, 0};
#pragma unroll 4
    for (int kk = 0; kk < 48; ++kk) {
        float aq = qs[r][kk];
        float4 b4 = *(const float4*)&kst[kk][cg * 4];
        acc.x += aq * b4.x; acc.y += aq * b4.y; acc.z += aq * b4.z; acc.w += aq * b4.w;
    }
    size_t base = ((size_t)h << 20) + ((size_t)(i0 + r) << 10) + j0 + cg * 4;
    float4 sv = *(float4*)&S[base];
    sv.x += acc.x; sv.y += acc.y; sv.z += acc.z; sv.w += acc.w;
    *(float4*)&S[base] = sv;
}

// ---------------------------------------------------------------------------
// softmax over last dim (1024) of S, in place; one block per (h,i) row
// ---------------------------------------------------------------------------
__global__ __launch_bounds__(256) void softmax_kernel(float* __restrict__ S) {
    float* x = S + ((size_t)blockIdx.x << 10);
    int t = threadIdx.x;
    int wid = t >> 6, lane = t & 63;
    __shared__ float sw[4], bres[2];
    float m = -1e30f;
    for (int c = t; c < 1024; c += 256) m = fmaxf(m, x[c]);
#pragma unroll
    for (int off = 32; off > 0; off >>= 1) m = fmaxf(m, __shfl_down(m, off));
    if (lane == 0) sw[wid] = m;
    __syncthreads();
    if (t == 0) bres[0] = fmaxf(fmaxf(sw[0], sw[1]), fmaxf(sw[2], sw[3]));
    __syncthreads();
    m = bres[0];
    float sum = 0.f;
    for (int c = t; c < 1024; c += 256) { float e = expf(x[c] - m); x[c] = e; sum += e; }
#pragma unroll
    for (int off = 32; off > 0; off >>= 1) sum += __shfl_down(sum, off);
    if (lane == 0) sw[wid] = sum;
    __syncthreads();
    if (t == 0) bres[1] = sw[0] + sw[1] + sw[2] + sw[3];
    __syncthreads();
    float inv = 1.0f / bres[1];
    for (int c = t; c < 1024; c += 256) x[c] *= inv;
}

// ---------------------------------------------------------------------------
// o[i, h*48+d] = sigmoid(g[i,h*48+d]) * sum_j P[h,i,j] * v[j, h*48+d]
// grid (NT/32, NH); 32 rows x 48 cols per block
// ---------------------------------------------------------------------------
__global__ __launch_bounds__(256) void attn_v_kernel(const float* __restrict__ S,
                                                     const float* __restrict__ v,
                                                     const float* __restrict__ g,
                                                     float* __restrict__ o) {
    __shared__ float Ps[32][33];
    __shared__ float vs[32][50];
    int h = blockIdx.y, i0 = blockIdx.x * 32;
    int t = threadIdx.x;
    int r = t >> 3, cg = t & 7, c0 = cg * 6;
    float acc[6] = {};
    for (int j0 = 0; j0 < NT; j0 += 32) {
        __syncthreads();
        for (int idx = t; idx < 1024; idx += 256) {
            int rr = idx >> 5, cc = idx & 31;
            Ps[rr][cc] = S[((size_t)h << 20) + ((size_t)(i0 + rr) << 10) + j0 + cc];
        }
        for (int idx = t; idx < 1536; idx += 256) {
            int rr = idx / 48, cc = idx % 48;
            vs[rr][cc] = v[(size_t)(j0 + rr) * CA + h * HD + cc];
        }
        __syncthreads();
#pragma unroll 4
        for (int jj = 0; jj < 32; ++jj) {
            float p = Ps[r][jj];
#pragma unroll
            for (int c = 0; c < 6; ++c) acc[c] += p * vs[jj][c0 + c];
        }
    }
    size_t base = (size_t)(i0 + r) * CA + h * HD + c0;
#pragma unroll
    for (int c = 0; c < 6; ++c) o[base + c] = sigmoidf_(g[base + c]) * acc[c];
}

// ---------------------------------------------------------------------------
// elementwise: out = sigmoid(gsrc)*m (+ add)
// ---------------------------------------------------------------------------
__global__ __launch_bounds__(256) void ew_gate_kernel(const float* __restrict__ gsrc,
                                                      const float* __restrict__ m,
                                                      const float* __restrict__ add,
                                                      float* __restrict__ out, int n) {
    int i = blockIdx.x * 256 + threadIdx.x;
    if (i < n) {
        float r = sigmoidf_(gsrc[i]) * m[i];
        if (add) r += add[i];
        out[i] = r;
    }
}

__global__ __launch_bounds__(256) void ew_silu_mul_kernel(float* __restrict__ h1,
                                                          const float* __restrict__ h2, int n) {
    int i = blockIdx.x * 256 + threadIdx.x;
    if (i < n) { float x = h1[i]; h1[i] = x * sigmoidf_(x) * h2[i]; }
}

__global__ __launch_bounds__(256) void copy_kernel(const float* __restrict__ in,
                                                   float* __restrict__ out, int n) {
    int i = blockIdx.x * 256 + threadIdx.x;
    if (i < n) out[i] = in[i];
}

// ---------------------------------------------------------------------------
extern "C" void kernel_launch(void* const* d_in, const int* in_sizes, int n_in,
                              void* d_out, int out_size, void* d_ws, size_t ws_size,
                              hipStream_t stream) {
    const float* a          = (const float*)d_in[0];
    const float* s          = (const float*)d_in[1];
    const float* z          = (const float*)d_in[2];
    const float* a1_sln_g   = (const float*)d_in[3];
    const float* a1_sln_b   = (const float*)d_in[4];
    const float* a1_sg_W    = (const float*)d_in[5];
    const float* a1_sg_b    = (const float*)d_in[6];
    const float* a1_sb_W    = (const float*)d_in[7];
    const float* Wq         = (const float*)d_in[8];
    const float* bq         = (const float*)d_in[9];
    const float* Wk         = (const float*)d_in[10];
    const float* Wv         = (const float*)d_in[11];
    const float* Wg         = (const float*)d_in[12];
    const float* Wo         = (const float*)d_in[13];
    const float* bo         = (const float*)d_in[14];
    const float* zln_g      = (const float*)d_in[15];
    const float* zln_b      = (const float*)d_in[16];
    const float* Wz         = (const float*)d_in[17];
    const float* Wlast      = (const float*)d_in[18];
    const float* blast      = (const float*)d_in[19];
    const float* a2_sln_g   = (const float*)d_in[20];
    const float* a2_sln_b   = (const float*)d_in[21];
    const float* a2_sg_W    = (const float*)d_in[22];
    const float* a2_sg_b    = (const float*)d_in[23];
    const float* a2_sb_W    = (const float*)d_in[24];
    const float* W1         = (const float*)d_in[25];
    const float* W2         = (const float*)d_in[26];
    const float* Wb         = (const float*)d_in[27];
    const float* Ws         = (const float*)d_in[28];
    const float* bs         = (const float*)d_in[29];

    const int nA = NT * CA;       // 786432
    const int nS = NT * CS;       // 393216
    const int nH = NT * 2 * CA;   // 1572864

    float* ws = (float*)d_ws;
    float* S     = ws;                         // 16 * 1024 * 1024
    float* aln   = S + (size_t)NH * NT * NT;   // LN(a) / LN(attn_out)
    float* x     = aln + nA;                   // adaLN output / t
    float* qb    = x + nA;
    float* kb    = qb + nA;
    float* vb    = kb + nA;
    float* gb    = vb + nA;
    float* ob    = gb + nA;                    // gated attention out
    float* oproj = ob + nA;
    float* attn  = oproj + nA;                 // attn_out (+residual)
    float* t1    = attn + nA;
    float* t2    = t1 + nA;
    float* sln   = t2 + nA;                    // LN(s), reused
    float* h1    = sln + nS;
    float* h2    = h1 + nH;

    float* out_a = (float*)d_out;
    float* out_s = out_a + nA;
    float* out_z = out_s + nS;

    dim3 b256(256);
    dim3 gemm_768(CA / 64, NT / 64);
    dim3 gemm_1536(2 * CA / 64, NT / 64);

    // ---- AttentionPairBias ----
    ln_kernel<<<NT, b256, 0, stream>>>(a, aln, nullptr, nullptr, CA);
    ln_kernel<<<NT, b256, 0, stream>>>(s, sln, a1_sln_g, a1_sln_b, CS);
    gemm_kernel<<<gemm_768, b256, 0, stream>>>(sln, a1_sg_W, a1_sg_b, t1, NT, CA, CS);
    gemm_kernel<<<gemm_768, b256, 0, stream>>>(sln, a1_sb_W, nullptr, t2, NT, CA, CS);
    ew_gate_kernel<<<nA / 256, b256, 0, stream>>>(t1, aln, t2, x, nA);

    gemm_kernel<<<gemm_768, b256, 0, stream>>>(x, Wq, bq, qb, NT, CA, CA);
    gemm_kernel<<<gemm_768, b256, 0, stream>>>(x, Wk, nullptr, kb, NT, CA, CA);
    gemm_kernel<<<gemm_768, b256, 0, stream>>>(x, Wv, nullptr, vb, NT, CA, CA);
    gemm_kernel<<<gemm_768, b256, 0, stream>>>(x, Wg, nullptr, gb, NT, CA, CA);

    // pair bias into S (+ z passthrough copy)
    z_bias_copy_kernel<<<NT * NT / 4, b256, 0, stream>>>(z, zln_g, zln_b, Wz, out_z, S);

    scores_kernel<<<dim3(NT / 32, NT / 32, NH), b256, 0, stream>>>(qb, kb, S);
    softmax_kernel<<<NH * NT, b256, 0, stream>>>(S);
    attn_v_kernel<<<dim3(NT / 32, NH), b256, 0, stream>>>(S, vb, gb, ob);

    gemm_kernel<<<gemm_768, b256, 0, stream>>>(ob, Wo, bo, oproj, NT, CA, CA);
    gemm_kernel<<<gemm_768, b256, 0, stream>>>(s, Wlast, blast, t1, NT, CA, CS);
    ew_gate_kernel<<<nA / 256, b256, 0, stream>>>(t1, oproj, a, attn, nA);  // + residual a

    // ---- ConditionedTransitionBlock ----
    ln_kernel<<<NT, b256, 0, stream>>>(attn, aln, nullptr, nullptr, CA);
    ln_kernel<<<NT, b256, 0, stream>>>(s, sln, a2_sln_g, a2_sln_b, CS);
    gemm_kernel<<<gemm_768, b256, 0, stream>>>(sln, a2_sg_W, a2_sg_b, t1, NT, CA, CS);
    gemm_kernel<<<gemm_768, b256, 0, stream>>>(sln, a2_sb_W, nullptr, t2, NT, CA, CS);
    ew_gate_kernel<<<nA / 256, b256, 0, stream>>>(t1, aln, t2, x, nA);  // t

    gemm_kernel<<<gemm_1536, b256, 0, stream>>>(x, W1, nullptr, h1, NT, 2 * CA, CA);
    gemm_kernel<<<gemm_1536, b256, 0, stream>>>(x, W2, nullptr, h2, NT, 2 * CA, CA);
    ew_silu_mul_kernel<<<nH / 256, b256, 0, stream>>>(h1, h2, nH);
    gemm_kernel<<<gemm_768, b256, 0, stream>>>(h1, Wb, nullptr, t2, NT, CA, 2 * CA);
    gemm_kernel<<<gemm_768, b256, 0, stream>>>(s, Ws, bs, t1, NT, CA, CS);
    ew_gate_kernel<<<nA / 256, b256, 0, stream>>>(t1, t2, attn, out_a, nA);

    // pass-through outputs
    copy_kernel<<<nS / 256, b256, 0, stream>>>(s, out_s, nS);
}